// Round 4
// baseline (3942.318 us; speedup 1.0000x reference)
//
#include <hip/hip_runtime.h>
#include <cstdint>
#include <cstddef>

// Problem constants: B=64, T=512, D=256, H=512
#define T_STEPS 512
#define D_DIM 256
#define H_DIM 512
#define B_SZ 64

// Scan decomposition: 4 column-groups of 128 cols per batch row.
// grid = 64 rows x 4 cg = 256 WGs of 512 threads; Wh slice (512x128 fp32 =
// 256 KB) lives entirely in registers (128 VGPR/thread), loaded once.
// Cross-WG exchange: per-kc PARTIAL (tag|acc) packets published immediately
// after each thread's 32-MAC chunk — no producer-side barrier/combine.
#define NCG 4
#define CGW (H_DIM / NCG)   // 128
#define NTH 512

// d_ws layout: zpart : uint64 [64 rows][2 parity][512 cols][4 kc]  = 2 MB
// No memset needed: poison 0xAAAAAAAA never equals a tag in 1..512.

// ---------------------------------------------------------------------------
// Kernel 1: xproj = inputs @ Wx + bias  ->  d_out  [B*T, H]
// ---------------------------------------------------------------------------
#define BM 64
#define BN 128
#define BK 32

__global__ __launch_bounds__(256)
void xproj_gemm(const float* __restrict__ A, const float* __restrict__ Bm,
                const float* __restrict__ bias, float* __restrict__ C,
                int M, int N, int K) {
    __shared__ float As[BK][BM];
    __shared__ float Bs[BK][BN];

    const int tid = threadIdx.x;
    const int tx = tid & 15;
    const int ty = tid >> 4;
    const int row0 = blockIdx.y * BM;
    const int col0 = blockIdx.x * BN;

    float acc[4][8];
    #pragma unroll
    for (int i = 0; i < 4; ++i)
        #pragma unroll
        for (int j = 0; j < 8; ++j) acc[i][j] = 0.0f;

    for (int kt = 0; kt < K; kt += BK) {
        #pragma unroll
        for (int i = 0; i < 2; ++i) {
            int q  = tid + i * 256;
            int m  = q >> 3;
            int k4 = (q & 7) << 2;
            float4 v = *(const float4*)&A[(size_t)(row0 + m) * K + kt + k4];
            As[k4 + 0][m] = v.x; As[k4 + 1][m] = v.y;
            As[k4 + 2][m] = v.z; As[k4 + 3][m] = v.w;
        }
        #pragma unroll
        for (int i = 0; i < 4; ++i) {
            int q  = tid + i * 256;
            int kk = q >> 5;
            int n4 = (q & 31) << 2;
            *(float4*)&Bs[kk][n4] = *(const float4*)&Bm[(size_t)(kt + kk) * N + col0 + n4];
        }
        __syncthreads();
        #pragma unroll
        for (int k = 0; k < BK; ++k) {
            float4 a  = *(const float4*)&As[k][ty << 2];
            float4 b0 = *(const float4*)&Bs[k][tx << 2];
            float4 b1 = *(const float4*)&Bs[k][(tx << 2) + 64];
            float av[4] = {a.x, a.y, a.z, a.w};
            float bv[8] = {b0.x, b0.y, b0.z, b0.w, b1.x, b1.y, b1.z, b1.w};
            #pragma unroll
            for (int i = 0; i < 4; ++i)
                #pragma unroll
                for (int j = 0; j < 8; ++j)
                    acc[i][j] = fmaf(av[i], bv[j], acc[i][j]);
        }
        __syncthreads();
    }

    float bv0[4], bv1[4];
    #pragma unroll
    for (int j = 0; j < 4; ++j) {
        bv0[j] = bias[col0 + (tx << 2) + j];
        bv1[j] = bias[col0 + (tx << 2) + 64 + j];
    }
    #pragma unroll
    for (int i = 0; i < 4; ++i) {
        int r = row0 + (ty << 2) + i;
        float4 o0 = make_float4(acc[i][0] + bv0[0], acc[i][1] + bv0[1],
                                acc[i][2] + bv0[2], acc[i][3] + bv0[3]);
        float4 o1 = make_float4(acc[i][4] + bv1[0], acc[i][5] + bv1[1],
                                acc[i][6] + bv1[2], acc[i][7] + bv1[3]);
        *(float4*)&C[(size_t)r * N + col0 + (tx << 2)]      = o0;
        *(float4*)&C[(size_t)r * N + col0 + (tx << 2) + 64] = o1;
    }
}

// ---------------------------------------------------------------------------
// Kernel 2: the scan. 256 WGs = 64 rows x 4 col-groups. Thread tid computes
// the kc=tid>>7 k-chunk partial for column cg*128 + (tid&127), publishes it
// as a (tag|partial) packet with NO intra-WG combine, then polls the 4
// partial packets for global column `tid`, sums them, and does LN/tanh.
// xp is folded into the kc==0 partial (fp add is commutative -> numerics
// identical to the previous xp+p0+p1+p2+p3 ordering).
// ---------------------------------------------------------------------------
__device__ __forceinline__ float tanh_fast(float x) {
    float ax = fabsf(x);
    float e  = __expf(2.0f * ax);
    float t  = 1.0f - 2.0f / (e + 1.0f);
    return copysignf(t, x);
}

__global__ __launch_bounds__(NTH)
void rnn_scan4(const float* __restrict__ Wh, const float* __restrict__ h0,
               const float* __restrict__ gamma, const float* __restrict__ beta,
               float* __restrict__ out,
               unsigned long long* __restrict__ zpart) {
    const int r   = blockIdx.x & (B_SZ - 1);   // row; quartet shares r
    const int cg  = blockIdx.x >> 6;           // 0..3
    const int tid = threadIdx.x;               // 0..511
    const int c   = tid & (CGW - 1);           // 0..127
    const int kc  = tid >> 7;                  // 0..3 (wave-uniform)

    __shared__ float h_s[H_DIM];
    __shared__ float wred_s[16];

    // Wh register slice: w[j] = Wh[kc*128 + j][cg*128 + c]
    float w[128];
    #pragma unroll
    for (int j = 0; j < 128; ++j)
        w[j] = Wh[(size_t)(kc * 128 + j) * H_DIM + cg * CGW + c];

    h_s[tid] = h0[r * H_DIM + tid];            // NTH == H_DIM
    const float g_own = gamma[tid];
    const float b_own = beta[tid];
    float* outrow = out + (size_t)r * T_STEPS * H_DIM;
    // zpart layout: [row][parity][col][kc]
    unsigned long long* zp0 = zpart + (size_t)r * 2 * H_DIM * NCG;
    __syncthreads();

    for (int t = 0; t < T_STEPS; ++t) {
        unsigned long long* zp = zp0 + (size_t)(t & 1) * H_DIM * NCG;
        const unsigned int tag = (unsigned int)(t + 1);

        // xp for own column, folded into the kc==0 partial
        float xp = (kc == 0) ? outrow[t * H_DIM + cg * CGW + c] : 0.0f;

        // partial: acc = sum_j w[j] * h[kc*128 + j]   (h reads broadcast)
        float acc = 0.0f;
        const float4* h4 = (const float4*)&h_s[kc * 128];
        #pragma unroll
        for (int j4 = 0; j4 < 32; ++j4) {
            float4 hv = h4[j4];
            acc = fmaf(w[4 * j4 + 0], hv.x, acc);
            acc = fmaf(w[4 * j4 + 1], hv.y, acc);
            acc = fmaf(w[4 * j4 + 2], hv.z, acc);
            acc = fmaf(w[4 * j4 + 3], hv.w, acc);
        }
        acc += xp;   // xp load completes here (data dep) — before publish

        // publish own partial packet immediately — no barrier, no combine
        unsigned long long pkt =
            ((unsigned long long)tag << 32) | (unsigned long long)__float_as_uint(acc);
        __hip_atomic_store(&zp[(size_t)(cg * CGW + c) * NCG + kc], pkt,
                           __ATOMIC_RELAXED, __HIP_MEMORY_SCOPE_AGENT);

        // poll the 4 partial packets for global column `tid`
        unsigned long long* pb = &zp[(size_t)tid * NCG];
        unsigned long long p0, p1, p2, p3;
        do {
            p0 = __hip_atomic_load(&pb[0], __ATOMIC_RELAXED, __HIP_MEMORY_SCOPE_AGENT);
            p1 = __hip_atomic_load(&pb[1], __ATOMIC_RELAXED, __HIP_MEMORY_SCOPE_AGENT);
            p2 = __hip_atomic_load(&pb[2], __ATOMIC_RELAXED, __HIP_MEMORY_SCOPE_AGENT);
            p3 = __hip_atomic_load(&pb[3], __ATOMIC_RELAXED, __HIP_MEMORY_SCOPE_AGENT);
        } while (((unsigned int)(p0 >> 32) != tag) | ((unsigned int)(p1 >> 32) != tag) |
                 ((unsigned int)(p2 >> 32) != tag) | ((unsigned int)(p3 >> 32) != tag));

        float z = ((__uint_as_float((unsigned int)p0)  + __uint_as_float((unsigned int)p1))
                  + __uint_as_float((unsigned int)p2)) + __uint_as_float((unsigned int)p3);

        // LN stats over 512: wave shuffle + LDS, combined redundantly by all
        float s = z, q = z * z;
        #pragma unroll
        for (int o = 32; o > 0; o >>= 1) {
            s += __shfl_down(s, o, 64);
            q += __shfl_down(q, o, 64);
        }
        const int wid = tid >> 6;
        if ((tid & 63) == 0) { wred_s[wid] = s; wred_s[8 + wid] = q; }
        __syncthreads();                                   // barrier B
        float S = 0.0f, Q = 0.0f;
        #pragma unroll
        for (int i = 0; i < 8; ++i) { S += wred_s[i]; Q += wred_s[8 + i]; }
        float mean = S * (1.0f / H_DIM);
        float var  = Q * (1.0f / H_DIM) - mean * mean;
        float rstd = rsqrtf(var + 1e-3f);                  // keras LN eps

        float hn = tanh_fast((z - mean) * rstd * g_own + b_own);
        if (kc == cg) outrow[t * H_DIM + tid] = hn;        // own slice store
        h_s[tid] = hn;            // safe: all h_s reads ended before barrier B
        __syncthreads();                                   // barrier C
    }
}

// ---------------------------------------------------------------------------
extern "C" void kernel_launch(void* const* d_in, const int* in_sizes, int n_in,
                              void* d_out, int out_size, void* d_ws, size_t ws_size,
                              hipStream_t stream) {
    const float* inputs = (const float*)d_in[0];  // [B,T,D]
    const float* h0     = (const float*)d_in[1];  // [B,H]
    const float* Wx     = (const float*)d_in[2];  // [D,H]
    const float* Wh     = (const float*)d_in[3];  // [H,H]
    const float* bias   = (const float*)d_in[4];  // [H]
    const float* gamma  = (const float*)d_in[5];  // [H]
    const float* beta   = (const float*)d_in[6];  // [H]
    float* out = (float*)d_out;                   // [B,T,H]

    unsigned long long* zpart = (unsigned long long*)d_ws;  // 2 MB

    const int M = B_SZ * T_STEPS;                 // 32768
    dim3 g1(H_DIM / BN, M / BM);                  // (4, 512)
    xproj_gemm<<<g1, 256, 0, stream>>>(inputs, Wx, bias, out, M, H_DIM, D_DIM);

    rnn_scan4<<<B_SZ * NCG, NTH, 0, stream>>>(Wh, h0, gamma, beta, out, zpart);
}

// Round 5
// 1853.540 us; speedup vs baseline: 2.1269x; 2.1269x over previous
//
#include <hip/hip_runtime.h>
#include <hip/hip_fp16.h>
#include <cstdint>
#include <cstddef>

// Problem constants: B=64, T=512, D=256, H=512
#define T_STEPS 512
#define D_DIM 256
#define H_DIM 512
#define B_SZ 64

// Scan: ONE workgroup per batch row, 1024 threads (16 waves, 4/SIMD, <=128
// VGPR). Full Wh lives on-CU as packed f16: 92 half2/thread in registers
// (368 KB/CU) + 18 uint2 rows in LDS (144 KB) = 512x512 weights. Column
// c = tid&511, k-half kh = tid>>9 (k-split x2, combined via LDS). All
// synchronization is intra-CU __syncthreads — no cross-WG flight at all.
#define NTH5 1024
#define WREG 92            // half2 pairs per thread in registers
#define WLDS 18            // uint2 rows in LDS (2 half2 each): 92+2*18 = 128

// ---------------------------------------------------------------------------
// Kernel 1: xproj = inputs @ Wx + bias  ->  d_out  [B*T, H]   (unchanged)
// ---------------------------------------------------------------------------
#define BM 64
#define BN 128
#define BK 32

__global__ __launch_bounds__(256)
void xproj_gemm(const float* __restrict__ A, const float* __restrict__ Bm,
                const float* __restrict__ bias, float* __restrict__ C,
                int M, int N, int K) {
    __shared__ float As[BK][BM];
    __shared__ float Bs[BK][BN];

    const int tid = threadIdx.x;
    const int tx = tid & 15;
    const int ty = tid >> 4;
    const int row0 = blockIdx.y * BM;
    const int col0 = blockIdx.x * BN;

    float acc[4][8];
    #pragma unroll
    for (int i = 0; i < 4; ++i)
        #pragma unroll
        for (int j = 0; j < 8; ++j) acc[i][j] = 0.0f;

    for (int kt = 0; kt < K; kt += BK) {
        #pragma unroll
        for (int i = 0; i < 2; ++i) {
            int q  = tid + i * 256;
            int m  = q >> 3;
            int k4 = (q & 7) << 2;
            float4 v = *(const float4*)&A[(size_t)(row0 + m) * K + kt + k4];
            As[k4 + 0][m] = v.x; As[k4 + 1][m] = v.y;
            As[k4 + 2][m] = v.z; As[k4 + 3][m] = v.w;
        }
        #pragma unroll
        for (int i = 0; i < 4; ++i) {
            int q  = tid + i * 256;
            int kk = q >> 5;
            int n4 = (q & 31) << 2;
            *(float4*)&Bs[kk][n4] = *(const float4*)&Bm[(size_t)(kt + kk) * N + col0 + n4];
        }
        __syncthreads();
        #pragma unroll
        for (int k = 0; k < BK; ++k) {
            float4 a  = *(const float4*)&As[k][ty << 2];
            float4 b0 = *(const float4*)&Bs[k][tx << 2];
            float4 b1 = *(const float4*)&Bs[k][(tx << 2) + 64];
            float av[4] = {a.x, a.y, a.z, a.w};
            float bv[8] = {b0.x, b0.y, b0.z, b0.w, b1.x, b1.y, b1.z, b1.w};
            #pragma unroll
            for (int i = 0; i < 4; ++i)
                #pragma unroll
                for (int j = 0; j < 8; ++j)
                    acc[i][j] = fmaf(av[i], bv[j], acc[i][j]);
        }
        __syncthreads();
    }

    float bv0[4], bv1[4];
    #pragma unroll
    for (int j = 0; j < 4; ++j) {
        bv0[j] = bias[col0 + (tx << 2) + j];
        bv1[j] = bias[col0 + (tx << 2) + 64 + j];
    }
    #pragma unroll
    for (int i = 0; i < 4; ++i) {
        int r = row0 + (ty << 2) + i;
        float4 o0 = make_float4(acc[i][0] + bv0[0], acc[i][1] + bv0[1],
                                acc[i][2] + bv0[2], acc[i][3] + bv0[3]);
        float4 o1 = make_float4(acc[i][4] + bv1[0], acc[i][5] + bv1[1],
                                acc[i][6] + bv1[2], acc[i][7] + bv1[3]);
        *(float4*)&C[(size_t)r * N + col0 + (tx << 2)]      = o0;
        *(float4*)&C[(size_t)r * N + col0 + (tx << 2) + 64] = o1;
    }
}

// ---------------------------------------------------------------------------
// Kernel 2: the scan, fully CU-local.
// ---------------------------------------------------------------------------
typedef _Float16 half2v __attribute__((ext_vector_type(2)));

__device__ __forceinline__ float fdot2u(unsigned int a, unsigned int b, float c) {
    // v_dot2_f32_f16: a.x*b.x + a.y*b.y + c
    return __builtin_amdgcn_fdot2(__builtin_bit_cast(half2v, a),
                                  __builtin_bit_cast(half2v, b), c, false);
}

__device__ __forceinline__ unsigned int pack_h2(float lo, float hi) {
    __half2 h = __floats2half2_rn(lo, hi);   // .x = lo (low 16 bits)
    return __builtin_bit_cast(unsigned int, h);
}

__device__ __forceinline__ float tanh_fast(float x) {
    float ax = fabsf(x);
    float e  = __expf(2.0f * ax);
    float t  = 1.0f - 2.0f / (e + 1.0f);
    return copysignf(t, x);
}

__global__ __launch_bounds__(NTH5, 4)   // 4 waves/EU -> cap 128 VGPR
void rnn_scan5(const float* __restrict__ Wh, const float* __restrict__ h0,
               const float* __restrict__ gamma, const float* __restrict__ beta,
               float* __restrict__ out) {
    const int r   = blockIdx.x;                // batch row
    const int tid = threadIdx.x;               // 0..1023
    const int c   = tid & (H_DIM - 1);         // column 0..511
    const int kh  = tid >> 9;                  // k-half 0/1 (wave-uniform)

    __shared__ uint2 wl2[WLDS][NTH5];                  // 144 KB weight slab
    __shared__ __align__(16) __half hh_s[H_DIM];       // h state, f16
    __shared__ float part_s[NTH5];                     // k-split partials
    __shared__ float wred_s[16];                       // LN wave partials

    // ---- one-time: load this thread's Wh column slice, pack to f16 ----
    // pair j in [0,128): k = kh*256 + 2j, 2j+1.  j<WREG -> regs; else LDS.
    unsigned int wreg[WREG];
    {
        const float* wcol = Wh + (size_t)(kh * 256) * H_DIM + c;
        #pragma unroll
        for (int j = 0; j < WREG; ++j) {
            float w0 = wcol[(size_t)(2 * j    ) * H_DIM];
            float w1 = wcol[(size_t)(2 * j + 1) * H_DIM];
            wreg[j] = pack_h2(w0, w1);
        }
        #pragma unroll
        for (int p = 0; p < WLDS; ++p) {
            int j0 = WREG + 2 * p;
            float a0 = wcol[(size_t)(2 * j0    ) * H_DIM];
            float a1 = wcol[(size_t)(2 * j0 + 1) * H_DIM];
            float a2 = wcol[(size_t)(2 * j0 + 2) * H_DIM];
            float a3 = wcol[(size_t)(2 * j0 + 3) * H_DIM];
            wl2[p][tid] = make_uint2(pack_h2(a0, a1), pack_h2(a2, a3));
        }
    }
    if (tid < H_DIM) hh_s[tid] = __float2half_rn(h0[r * H_DIM + tid]);
    const float g_own = (tid < H_DIM) ? gamma[tid] : 0.0f;
    const float b_own = (tid < H_DIM) ? beta[tid]  : 0.0f;
    float* outrow = out + (size_t)r * T_STEPS * H_DIM;
    __syncthreads();

    for (int t = 0; t < T_STEPS; ++t) {
        // xp prefetch for own column (consumed after the GEMM)
        float xp = (tid < H_DIM) ? outrow[t * H_DIM + tid] : 0.0f;

        // partial dot over this thread's 256-k half (f16 dot2, h broadcast)
        const uint4* hu4 = ((const uint4*)hh_s) + kh * 32;            // j 0..91
        const uint2* hu2 = ((const uint2*)hh_s) + kh * 64 + (WREG >> 1); // j>=92
        float acc = 0.0f;
        #pragma unroll
        for (int j4 = 0; j4 < WREG / 4; ++j4) {     // 23 x uint4 = 92 pairs
            uint4 hv = hu4[j4];
            acc = fdot2u(wreg[4 * j4 + 0], hv.x, acc);
            acc = fdot2u(wreg[4 * j4 + 1], hv.y, acc);
            acc = fdot2u(wreg[4 * j4 + 2], hv.z, acc);
            acc = fdot2u(wreg[4 * j4 + 3], hv.w, acc);
        }
        #pragma unroll
        for (int p = 0; p < WLDS; ++p) {            // 18 x uint2 = 36 pairs
            uint2 wv = wl2[p][tid];
            uint2 hv = hu2[p];
            acc = fdot2u(wv.x, hv.x, acc);
            acc = fdot2u(wv.y, hv.y, acc);
        }
        part_s[tid] = acc;
        __syncthreads();                            // B1: partials ready

        // combine k-halves + xp; LN stats over the 512 columns
        float z = 0.0f, s = 0.0f, q = 0.0f;
        if (tid < H_DIM) {
            z = part_s[tid] + part_s[tid + H_DIM] + xp;
            s = z; q = z * z;
        }
        #pragma unroll
        for (int o = 32; o > 0; o >>= 1) {
            s += __shfl_down(s, o, 64);
            q += __shfl_down(q, o, 64);
        }
        if (tid < H_DIM && (tid & 63) == 0) {
            wred_s[tid >> 6]     = s;
            wred_s[8 + (tid >> 6)] = q;
        }
        __syncthreads();                            // B2: stats ready
        float S = 0.0f, Q = 0.0f;
        #pragma unroll
        for (int i = 0; i < 8; ++i) { S += wred_s[i]; Q += wred_s[8 + i]; }
        float mean = S * (1.0f / H_DIM);
        float var  = Q * (1.0f / H_DIM) - mean * mean;
        float rstd = rsqrtf(var + 1e-3f);           // keras LN eps

        if (tid < H_DIM) {
            float hn = tanh_fast((z - mean) * rstd * g_own + b_own);
            outrow[t * H_DIM + tid] = hn;           // overwrite xproj slot
            hh_s[tid] = __float2half_rn(hn);        // safe: reads ended pre-B1
        }
        __syncthreads();                            // B3: h ready for t+1
    }
}

// ---------------------------------------------------------------------------
extern "C" void kernel_launch(void* const* d_in, const int* in_sizes, int n_in,
                              void* d_out, int out_size, void* d_ws, size_t ws_size,
                              hipStream_t stream) {
    const float* inputs = (const float*)d_in[0];  // [B,T,D]
    const float* h0     = (const float*)d_in[1];  // [B,H]
    const float* Wx     = (const float*)d_in[2];  // [D,H]
    const float* Wh     = (const float*)d_in[3];  // [H,H]
    const float* bias   = (const float*)d_in[4];  // [H]
    const float* gamma  = (const float*)d_in[5];  // [H]
    const float* beta   = (const float*)d_in[6];  // [H]
    float* out = (float*)d_out;                   // [B,T,H]

    const int M = B_SZ * T_STEPS;                 // 32768
    dim3 g1(H_DIM / BN, M / BM);                  // (4, 512)
    xproj_gemm<<<g1, 256, 0, stream>>>(inputs, Wx, bias, out, M, H_DIM, D_DIM);

    rnn_scan5<<<B_SZ, NTH5, 0, stream>>>(Wh, h0, gamma, beta, out);
}